// Round 5
// baseline (82.846 us; speedup 1.0000x reference)
//
#include <hip/hip_runtime.h>

#define N 8192
#define D 128

typedef __attribute__((ext_vector_type(8))) short bf16x8;
typedef __attribute__((ext_vector_type(4))) float f32x4;
typedef unsigned int u32;
typedef unsigned short u16;

__device__ __forceinline__ u16 f2bf(float f) {
    u32 u = __float_as_uint(f);
    u += 0x7FFF + ((u >> 16) & 1);   // round-to-nearest-even
    return (u16)(u >> 16);
}

// ---- kernel 1: streaming bf16 copy + row sqnorm + init (no LDS) ------------
// 512 blocks x 256 thr; 16 lanes per row, 16 rows per block.
__global__ __launch_bounds__(256) void k_prep(const float* __restrict__ x,
                                              u16* __restrict__ xbf,
                                              float* __restrict__ sq,
                                              u32* __restrict__ minkey,
                                              u32* __restrict__ ctr) {
    const int tid = threadIdx.x;
    const int r = blockIdx.x * 16 + (tid >> 4);
    const int lr = tid & 15;
    const float4* src = (const float4*)(x + (size_t)r * D + lr * 8);
    float4 v0 = src[0], v1 = src[1];
    union { u16 h[8]; uint4 v; } o;
    o.h[0] = f2bf(v0.x); o.h[1] = f2bf(v0.y); o.h[2] = f2bf(v0.z); o.h[3] = f2bf(v0.w);
    o.h[4] = f2bf(v1.x); o.h[5] = f2bf(v1.y); o.h[6] = f2bf(v1.z); o.h[7] = f2bf(v1.w);
    *(uint4*)(xbf + (size_t)r * D + lr * 8) = o.v;
    float s = v0.x * v0.x + v0.y * v0.y + v0.z * v0.z + v0.w * v0.w
            + v1.x * v1.x + v1.y * v1.y + v1.z * v1.z + v1.w * v1.w;
    s += __shfl_xor(s, 1); s += __shfl_xor(s, 2);
    s += __shfl_xor(s, 4); s += __shfl_xor(s, 8);
    if (lr == 0) { sq[r] = s; minkey[r] = 0xFFFFFFFFu; }
    if (blockIdx.x == 0 && tid < 128) ctr[tid] = 0;
}

// ---- kernel 2: barrier-free, LDS-free gram + min/max + fused final ---------
// 2048 waves: wave = (row-group rg of 64 rows) x (sweep sw of 512 cols).
// A frags register-resident; B frags streamed from L2 per K-step.
__global__ __launch_bounds__(256, 2) void k_neg(const u16* __restrict__ xbf,
                                                const float* __restrict__ sq,
                                                u32* __restrict__ minkey,
                                                u32* __restrict__ ap2,
                                                u32* __restrict__ ctr,
                                                float* __restrict__ out) {
    const int tid = threadIdx.x, lane = tid & 63;
    const int wid = blockIdx.x * 4 + (tid >> 6);
    const int rg = wid >> 4, sw = wid & 15;
    const int row0 = rg * 64, cs = sw * 512;
    const int lr = lane & 15, lg = lane >> 4;
    const int td = ((rg >> 3) == sw) ? (rg & 7) : -1;   // diag tile idx in sweep
    const float INF = __int_as_float(0x7F800000);

    // A fragments: 64 rows x 128 K, loaded once (64 VGPR)
    bf16x8 af[4][4];
#pragma unroll
    for (int f = 0; f < 4; ++f)
#pragma unroll
        for (int kk = 0; kk < 4; ++kk)
            af[f][kk] = *(const bf16x8*)(xbf + (size_t)(row0 + f * 16 + lr) * D + kk * 32 + lg * 8);

    float rmin[4][4] = {{INF, INF, INF, INF}, {INF, INF, INF, INF},
                        {INF, INF, INF, INF}, {INF, INF, INF, INF}};

#pragma unroll
    for (int t = 0; t < 8; ++t) {
        const int c0 = cs + t * 64;
        float sjv[4];
#pragma unroll
        for (int fj = 0; fj < 4; ++fj) sjv[fj] = sq[c0 + fj * 16 + lr];

        f32x4 acc[4][4] = {};
#pragma unroll
        for (int kk = 0; kk < 4; ++kk) {
            bf16x8 bq[4];
#pragma unroll
            for (int fj = 0; fj < 4; ++fj)
                bq[fj] = *(const bf16x8*)(xbf + (size_t)(c0 + fj * 16 + lr) * D + kk * 32 + lg * 8);
#pragma unroll
            for (int fi = 0; fi < 4; ++fi)
#pragma unroll
                for (int fj = 0; fj < 4; ++fj)
                    acc[fi][fj] = __builtin_amdgcn_mfma_f32_16x16x32_bf16(
                        af[fi][kk], bq[fj], acc[fi][fj], 0, 0, 0);
        }

        if (t == td) {
            // diagonal tile: fj==fi fragments are the same-cluster block -> d_ap
#pragma unroll
            for (int fi = 0; fi < 4; ++fi) {
                float rmx[4] = {-INF, -INF, -INF, -INF};
#pragma unroll
                for (int jj = 0; jj < 4; ++jj)
#pragma unroll
                    for (int fj = 0; fj < 4; ++fj) {
                        float v = fmaf(-2.f, acc[fi][fj][jj], sjv[fj]);
                        if (fj == fi) rmx[jj] = fmaxf(rmx[jj], v);
                        else rmin[fi][jj] = fminf(rmin[fi][jj], v);
                    }
#pragma unroll
                for (int jj = 0; jj < 4; ++jj) {
                    float v = rmx[jj];
                    v = fmaxf(v, __shfl_xor(v, 1));
                    v = fmaxf(v, __shfl_xor(v, 2));
                    v = fmaxf(v, __shfl_xor(v, 4));
                    v = fmaxf(v, __shfl_xor(v, 8));
                    if (lr == 0) {
                        const int gi = row0 + fi * 16 + lg * 4 + jj;
                        ap2[gi] = __float_as_uint(fmaxf(sq[gi] + v, 0.f));
                    }
                }
            }
        } else {
#pragma unroll
            for (int fi = 0; fi < 4; ++fi)
#pragma unroll
                for (int jj = 0; jj < 4; ++jj)
#pragma unroll
                    for (int fj = 0; fj < 4; ++fj)
                        rmin[fi][jj] = fminf(rmin[fi][jj],
                                             fmaf(-2.f, acc[fi][fj][jj], sjv[fj]));
        }
    }

    // per-wave reduce + one atomicMin per output row
#pragma unroll
    for (int fi = 0; fi < 4; ++fi)
#pragma unroll
        for (int jj = 0; jj < 4; ++jj) {
            float v = rmin[fi][jj];
            v = fminf(v, __shfl_xor(v, 1));
            v = fminf(v, __shfl_xor(v, 2));
            v = fminf(v, __shfl_xor(v, 4));
            v = fminf(v, __shfl_xor(v, 8));
            if (lr == 0) {
                const int gi = row0 + fi * 16 + lg * 4 + jj;
                atomicMin(&minkey[gi], __float_as_uint(fmaxf(sq[gi] + v, 0.f)));
            }
        }

    // fused finalization: 16th wave of each row-group writes the output
    __threadfence();
    u32 old = 0;
    if (lane == 0) old = atomicAdd(&ctr[rg], 1u);
    old = __shfl(old, 0);
    if (old == 15u) {
        __threadfence();
        const int gi = row0 + lane;
        u32 mk = atomicAdd(&minkey[gi], 0u);   // atomic read (L2-coherent)
        u32 ab = atomicOr(&ap2[gi], 0u);       // atomic read
        out[gi] = fmaxf(sqrtf(__uint_as_float(ab)) - sqrtf(__uint_as_float(mk)) + 1.f, 0.f);
    }
}

extern "C" void kernel_launch(void* const* d_in, const int* in_sizes, int n_in,
                              void* d_out, int out_size, void* d_ws, size_t ws_size,
                              hipStream_t stream) {
    const float* x = (const float*)d_in[0];
    float* out = (float*)d_out;

    char* ws = (char*)d_ws;
    u16* xbf = (u16*)ws;                                // 2 MB bf16 copy
    float* sq = (float*)(ws + 2097152);                 // 32 KB
    u32* minkey = (u32*)(ws + 2097152 + 32768);         // 32 KB
    u32* ap2 = (u32*)(ws + 2097152 + 65536);            // 32 KB
    u32* ctr = (u32*)(ws + 2097152 + 98304);            // 512 B

    k_prep<<<N / 16, 256, 0, stream>>>(x, xbf, sq, minkey, ctr);
    k_neg<<<512, 256, 0, stream>>>(xbf, sq, minkey, ap2, ctr, out);
}

// Round 6
// 67.709 us; speedup vs baseline: 1.2236x; 1.2236x over previous
//
#include <hip/hip_runtime.h>

#define N 8192
#define D 128

typedef __attribute__((ext_vector_type(8))) short bf16x8;
typedef __attribute__((ext_vector_type(4))) float f32x4;
typedef unsigned int u32;
typedef unsigned short u16;

__device__ __forceinline__ u16 f2bf(float f) {
    u32 u = __float_as_uint(f);
    u += 0x7FFF + ((u >> 16) & 1);   // round-to-nearest-even
    return (u16)(u >> 16);
}

// async global->LDS, 16B/lane; dst base wave-uniform (HW adds lane*16)
__device__ __forceinline__ void gl_lds16(const u16* g, u16* l) {
    __builtin_amdgcn_global_load_lds(
        (const __attribute__((address_space(1))) u32*)g,
        (__attribute__((address_space(3))) u32*)l, 16, 0, 0);
}

// ---- kernel 1: streaming bf16 copy + row sqnorm + init ---------------------
__global__ __launch_bounds__(256) void k_prep(const float* __restrict__ x,
                                              u16* __restrict__ xbf,
                                              float* __restrict__ sq,
                                              u32* __restrict__ minkey,
                                              u32* __restrict__ ctr) {
    const int tid = threadIdx.x;
    const int r = blockIdx.x * 16 + (tid >> 4);
    const int lr = tid & 15;
    const float4* src = (const float4*)(x + (size_t)r * D + lr * 8);
    float4 v0 = src[0], v1 = src[1];
    union { u16 h[8]; uint4 v; } o;
    o.h[0] = f2bf(v0.x); o.h[1] = f2bf(v0.y); o.h[2] = f2bf(v0.z); o.h[3] = f2bf(v0.w);
    o.h[4] = f2bf(v1.x); o.h[5] = f2bf(v1.y); o.h[6] = f2bf(v1.z); o.h[7] = f2bf(v1.w);
    *(uint4*)(xbf + (size_t)r * D + lr * 8) = o.v;
    float s = v0.x * v0.x + v0.y * v0.y + v0.z * v0.z + v0.w * v0.w
            + v1.x * v1.x + v1.y * v1.y + v1.z * v1.z + v1.w * v1.w;
    s += __shfl_xor(s, 1); s += __shfl_xor(s, 2);
    s += __shfl_xor(s, 4); s += __shfl_xor(s, 8);
    if (lr == 0) { sq[r] = s; minkey[r] = 0xFFFFFFFFu; }
    if (blockIdx.x == 0 && tid < 32) ctr[tid] = 0;
}

// ---- kernel 2: gram via MFMA; A in regs, B double-buffered LDS -------------
// grid (32,8): block = rows [bi*256,+256) x cols [cg*1024,+1024), 8 waves.
// LDS: B 2x32 KB. Wave (wr,wc) owns 64x64 per 128-col tile.
__global__ __launch_bounds__(512, 2) void k_neg(const u16* __restrict__ xbf,
                                                const float* __restrict__ sq,
                                                u32* __restrict__ minkey,
                                                u32* __restrict__ ap2,
                                                u32* __restrict__ ctr,
                                                float* __restrict__ out) {
    __shared__ __align__(16) u16 Bl[2][128 * 128];   // 2 x 32 KB
    __shared__ u32 sflag;

    const int bi = blockIdx.x;          // row panel (256 rows)
    const int cg = blockIdx.y;          // col group (1024 cols)
    const int row0 = bi * 256, col00 = cg * 1024;
    const int tid = threadIdx.x;
    const int lane = tid & 63, wave = tid >> 6;
    const int lr = lane & 15, lg = lane >> 4;
    const int wr = wave >> 1, wc = wave & 1;
    const float INF = __int_as_float(0x7F800000);

    // this wave's diagonal tile index (cluster-aligned): fj==fi frags are
    // exactly the same-cluster 16-block there.
    const int tdiag = (cg == (bi >> 2) && wc == (wr & 1))
                      ? 2 * (bi & 3) + (wr >> 1) : -1;

    // stage B tile 0 (swizzle via pre-swizzled global chunk)
#pragma unroll
    for (int it = 0; it < 4; ++it) {
        const int rb0 = wave * 16 + it * 4;
        const int r = rb0 + (lane >> 4);
        gl_lds16(xbf + (size_t)(col00 + r) * D + ((lr ^ (r & 7)) * 8),
                 Bl[0] + rb0 * 128);
    }

    // A fragments register-resident: 64 rows x 128 K (64 VGPR), loaded once
    bf16x8 af[4][4];
#pragma unroll
    for (int f = 0; f < 4; ++f)
#pragma unroll
        for (int kk = 0; kk < 4; ++kk)
            af[f][kk] = *(const bf16x8*)(xbf +
                (size_t)(row0 + wr * 64 + f * 16 + lr) * D + kk * 32 + lg * 8);

    // preload sq for all 8 tiles' col fragments (32 VGPR)
    float sjp[8][4];
#pragma unroll
    for (int t = 0; t < 8; ++t)
#pragma unroll
        for (int fj = 0; fj < 4; ++fj)
            sjp[t][fj] = sq[col00 + t * 128 + wc * 64 + fj * 16 + lr];

    float rmin[4][4] = {{INF, INF, INF, INF}, {INF, INF, INF, INF},
                        {INF, INF, INF, INF}, {INF, INF, INF, INF}};

    __syncthreads();   // B0 resident
    int cur = 0;

    for (int t = 0; t < 8; ++t) {
        if (t + 1 < 8) {   // prefetch next B tile before compute (T14)
            const int c0n = col00 + (t + 1) * 128;
#pragma unroll
            for (int it = 0; it < 4; ++it) {
                const int rb0 = wave * 16 + it * 4;
                const int r = rb0 + (lane >> 4);
                gl_lds16(xbf + (size_t)(c0n + r) * D + ((lr ^ (r & 7)) * 8),
                         Bl[cur ^ 1] + rb0 * 128);
            }
        }

        const u16* Bp = Bl[cur];
        f32x4 acc[4][4] = {};
#pragma unroll
        for (int kk = 0; kk < 4; ++kk) {
            const int kx = (kk * 64 + lg * 16) ^ ((lr & 7) << 4);
            bf16x8 bq[4];
#pragma unroll
            for (int fj = 0; fj < 4; ++fj)
                bq[fj] = *(const bf16x8*)((const char*)Bp +
                         (wc * 64 + fj * 16 + lr) * 256 + kx);
#pragma unroll
            for (int fi = 0; fi < 4; ++fi)
#pragma unroll
                for (int fj = 0; fj < 4; ++fj)
                    acc[fi][fj] = __builtin_amdgcn_mfma_f32_16x16x32_bf16(
                        af[fi][kk], bq[fj], acc[fi][fj], 0, 0, 0);
        }

        if (t == tdiag) {
#pragma unroll
            for (int fi = 0; fi < 4; ++fi) {
                float rmx[4] = {-INF, -INF, -INF, -INF};
#pragma unroll
                for (int jj = 0; jj < 4; ++jj)
#pragma unroll
                    for (int fj = 0; fj < 4; ++fj) {
                        float v = fmaf(-2.f, acc[fi][fj][jj], sjp[t][fj]);
                        if (fj == fi) rmx[jj] = fmaxf(rmx[jj], v);
                        else rmin[fi][jj] = fminf(rmin[fi][jj], v);
                    }
#pragma unroll
                for (int jj = 0; jj < 4; ++jj) {
                    float v = rmx[jj];
                    v = fmaxf(v, __shfl_xor(v, 1));
                    v = fmaxf(v, __shfl_xor(v, 2));
                    v = fmaxf(v, __shfl_xor(v, 4));
                    v = fmaxf(v, __shfl_xor(v, 8));
                    if (lr == 0) {
                        const int gi = row0 + wr * 64 + fi * 16 + lg * 4 + jj;
                        ap2[gi] = __float_as_uint(fmaxf(sq[gi] + v, 0.f));
                    }
                }
            }
        } else {
#pragma unroll
            for (int fi = 0; fi < 4; ++fi)
#pragma unroll
                for (int jj = 0; jj < 4; ++jj)
#pragma unroll
                    for (int fj = 0; fj < 4; ++fj)
                        rmin[fi][jj] = fminf(rmin[fi][jj],
                                             fmaf(-2.f, acc[fi][fj][jj], sjp[t][fj]));
        }

        __syncthreads();   // drains next-tile staging + read fence
        cur ^= 1;
    }

    // per-wave reduce + one atomicMin per row
#pragma unroll
    for (int fi = 0; fi < 4; ++fi)
#pragma unroll
        for (int jj = 0; jj < 4; ++jj) {
            float v = rmin[fi][jj];
            v = fminf(v, __shfl_xor(v, 1));
            v = fminf(v, __shfl_xor(v, 2));
            v = fminf(v, __shfl_xor(v, 4));
            v = fminf(v, __shfl_xor(v, 8));
            if (lr == 0) {
                const int gi = row0 + wr * 64 + fi * 16 + lg * 4 + jj;
                atomicMin(&minkey[gi], __float_as_uint(fmaxf(sq[gi] + v, 0.f)));
            }
        }

    // fused finalization: last of the 8 blocks for this row panel writes out
    __threadfence();
    __syncthreads();
    if (tid == 0) sflag = atomicAdd(&ctr[bi], 1u);
    __syncthreads();
    if (sflag == 7u && tid < 256) {
        __threadfence();
        const int gi = row0 + tid;
        u32 mk = atomicAdd(&minkey[gi], 0u);   // coherent read
        u32 ab = atomicOr(&ap2[gi], 0u);       // coherent read
        out[gi] = fmaxf(sqrtf(__uint_as_float(ab)) - sqrtf(__uint_as_float(mk)) + 1.f,
                        0.f);
    }
}

extern "C" void kernel_launch(void* const* d_in, const int* in_sizes, int n_in,
                              void* d_out, int out_size, void* d_ws, size_t ws_size,
                              hipStream_t stream) {
    const float* x = (const float*)d_in[0];
    float* out = (float*)d_out;

    char* ws = (char*)d_ws;
    u16* xbf = (u16*)ws;                                // 2 MB bf16 copy
    float* sq = (float*)(ws + 2097152);                 // 32 KB
    u32* minkey = (u32*)(ws + 2097152 + 32768);         // 32 KB
    u32* ap2 = (u32*)(ws + 2097152 + 65536);            // 32 KB
    u32* ctr = (u32*)(ws + 2097152 + 98304);            // 128 B

    k_prep<<<N / 16, 256, 0, stream>>>(x, xbf, sq, minkey, ctr);
    k_neg<<<dim3(32, 8), 512, 0, stream>>>(xbf, sq, minkey, ap2, ctr, out);
}

// Round 7
// 66.303 us; speedup vs baseline: 1.2495x; 1.0212x over previous
//
#include <hip/hip_runtime.h>

#define N 8192
#define D 128

typedef __attribute__((ext_vector_type(8))) short bf16x8;
typedef __attribute__((ext_vector_type(4))) float f32x4;
typedef unsigned int u32;
typedef unsigned short u16;

__device__ __forceinline__ u16 f2bf(float f) {
    u32 u = __float_as_uint(f);
    u += 0x7FFF + ((u >> 16) & 1);   // round-to-nearest-even
    return (u16)(u >> 16);
}

// async global->LDS, 16B/lane; dst base wave-uniform (HW adds lane*16)
__device__ __forceinline__ void gl_lds16(const u16* g, u16* l) {
    __builtin_amdgcn_global_load_lds(
        (const __attribute__((address_space(1))) u32*)g,
        (__attribute__((address_space(3))) u32*)l, 16, 0, 0);
}

// ---- kernel 1: streaming bf16 copy + row sqnorm + init ---------------------
__global__ __launch_bounds__(256) void k_prep(const float* __restrict__ x,
                                              u16* __restrict__ xbf,
                                              float* __restrict__ sq,
                                              u32* __restrict__ minkey,
                                              u32* __restrict__ ctr) {
    const int tid = threadIdx.x;
    const int r = blockIdx.x * 16 + (tid >> 4);
    const int lr = tid & 15;
    const float4* src = (const float4*)(x + (size_t)r * D + lr * 8);
    float4 v0 = src[0], v1 = src[1];
    union { u16 h[8]; uint4 v; } o;
    o.h[0] = f2bf(v0.x); o.h[1] = f2bf(v0.y); o.h[2] = f2bf(v0.z); o.h[3] = f2bf(v0.w);
    o.h[4] = f2bf(v1.x); o.h[5] = f2bf(v1.y); o.h[6] = f2bf(v1.z); o.h[7] = f2bf(v1.w);
    *(uint4*)(xbf + (size_t)r * D + lr * 8) = o.v;
    float s = v0.x * v0.x + v0.y * v0.y + v0.z * v0.z + v0.w * v0.w
            + v1.x * v1.x + v1.y * v1.y + v1.z * v1.z + v1.w * v1.w;
    s += __shfl_xor(s, 1); s += __shfl_xor(s, 2);
    s += __shfl_xor(s, 4); s += __shfl_xor(s, 8);
    if (lr == 0) { sq[r] = s; minkey[r] = 0xFFFFFFFFu; }
    if (blockIdx.x == 0 && tid < 32) ctr[tid] = 0;
}

// ---- kernel 2: gram via MFMA; A in regs (loaded once), B dbuf LDS ----------
// grid (32,8): block = rows [bi*256,+256) x cols [cg*1024,+1024), 8 waves.
// launch_bounds(512,1): do NOT cap VGPRs — af must stay register-resident.
__global__ __launch_bounds__(512, 1) void k_neg(const u16* __restrict__ xbf,
                                                const float* __restrict__ sq,
                                                u32* __restrict__ minkey,
                                                u32* __restrict__ ap2,
                                                u32* __restrict__ ctr,
                                                float* __restrict__ out) {
    __shared__ __align__(16) u16 Bl[2][128 * 128];   // 2 x 32 KB
    __shared__ u32 sflag;

    const int bi = blockIdx.x;          // row panel (256 rows)
    const int cg = blockIdx.y;          // col group (1024 cols)
    const int row0 = bi * 256, col00 = cg * 1024;
    const int tid = threadIdx.x;
    const int lane = tid & 63, wave = tid >> 6;
    const int lr = lane & 15, lg = lane >> 4;
    const int wr = wave >> 1, wc = wave & 1;
    const float INF = __int_as_float(0x7F800000);

    // this wave's diagonal tile index (cluster-aligned): fj==fi frags are
    // exactly the same-cluster 16-block there.
    const int tdiag = (cg == (bi >> 2) && wc == (wr & 1))
                      ? 2 * (bi & 3) + (wr >> 1) : -1;

    // stage B tile 0 (swizzle via pre-swizzled global chunk)
#pragma unroll
    for (int it = 0; it < 4; ++it) {
        const int rb0 = wave * 16 + it * 4;
        const int r = rb0 + (lane >> 4);
        gl_lds16(xbf + (size_t)(col00 + r) * D + ((lr ^ (r & 7)) * 8),
                 Bl[0] + rb0 * 128);
    }

    // A fragments register-resident: 64 rows x 128 K (64 VGPR), loaded once
    bf16x8 af[4][4];
#pragma unroll
    for (int f = 0; f < 4; ++f)
#pragma unroll
        for (int kk = 0; kk < 4; ++kk)
            af[f][kk] = *(const bf16x8*)(xbf +
                (size_t)(row0 + wr * 64 + f * 16 + lr) * D + kk * 32 + lg * 8);

    float rmin[4][4] = {{INF, INF, INF, INF}, {INF, INF, INF, INF},
                        {INF, INF, INF, INF}, {INF, INF, INF, INF}};

    __syncthreads();   // B0 resident
    int cur = 0;

    for (int t = 0; t < 8; ++t) {
        const int c0 = col00 + t * 128;
        if (t + 1 < 8) {   // prefetch next B tile before compute (T14)
            const int c0n = c0 + 128;
#pragma unroll
            for (int it = 0; it < 4; ++it) {
                const int rb0 = wave * 16 + it * 4;
                const int r = rb0 + (lane >> 4);
                gl_lds16(xbf + (size_t)(c0n + r) * D + ((lr ^ (r & 7)) * 8),
                         Bl[cur ^ 1] + rb0 * 128);
            }
        }

        // sq for this tile's col fragments (consumed after MFMA: latency hidden)
        float sjv[4];
#pragma unroll
        for (int fj = 0; fj < 4; ++fj)
            sjv[fj] = sq[c0 + wc * 64 + fj * 16 + lr];

        const u16* Bp = Bl[cur];
        f32x4 acc[4][4] = {};
#pragma unroll
        for (int kk = 0; kk < 4; ++kk) {
            const int kx = (kk * 64 + lg * 16) ^ ((lr & 7) << 4);
            bf16x8 bq[4];
#pragma unroll
            for (int fj = 0; fj < 4; ++fj)
                bq[fj] = *(const bf16x8*)((const char*)Bp +
                         (wc * 64 + fj * 16 + lr) * 256 + kx);
#pragma unroll
            for (int fi = 0; fi < 4; ++fi)
#pragma unroll
                for (int fj = 0; fj < 4; ++fj)
                    acc[fi][fj] = __builtin_amdgcn_mfma_f32_16x16x32_bf16(
                        af[fi][kk], bq[fj], acc[fi][fj], 0, 0, 0);
        }

        if (t == tdiag) {
#pragma unroll
            for (int fi = 0; fi < 4; ++fi) {
                float rmx[4] = {-INF, -INF, -INF, -INF};
#pragma unroll
                for (int jj = 0; jj < 4; ++jj)
#pragma unroll
                    for (int fj = 0; fj < 4; ++fj) {
                        float v = fmaf(-2.f, acc[fi][fj][jj], sjv[fj]);
                        if (fj == fi) rmx[jj] = fmaxf(rmx[jj], v);
                        else rmin[fi][jj] = fminf(rmin[fi][jj], v);
                    }
#pragma unroll
                for (int jj = 0; jj < 4; ++jj) {
                    float v = rmx[jj];
                    v = fmaxf(v, __shfl_xor(v, 1));
                    v = fmaxf(v, __shfl_xor(v, 2));
                    v = fmaxf(v, __shfl_xor(v, 4));
                    v = fmaxf(v, __shfl_xor(v, 8));
                    if (lr == 0) {
                        const int gi = row0 + wr * 64 + fi * 16 + lg * 4 + jj;
                        ap2[gi] = __float_as_uint(fmaxf(sq[gi] + v, 0.f));
                    }
                }
            }
        } else {
#pragma unroll
            for (int fi = 0; fi < 4; ++fi)
#pragma unroll
                for (int jj = 0; jj < 4; ++jj)
#pragma unroll
                    for (int fj = 0; fj < 4; ++fj)
                        rmin[fi][jj] = fminf(rmin[fi][jj],
                                             fmaf(-2.f, acc[fi][fj][jj], sjv[fj]));
        }

        __syncthreads();   // drains next-tile staging + read fence
        cur ^= 1;
    }

    // per-wave reduce + one atomicMin per row
#pragma unroll
    for (int fi = 0; fi < 4; ++fi)
#pragma unroll
        for (int jj = 0; jj < 4; ++jj) {
            float v = rmin[fi][jj];
            v = fminf(v, __shfl_xor(v, 1));
            v = fminf(v, __shfl_xor(v, 2));
            v = fminf(v, __shfl_xor(v, 4));
            v = fminf(v, __shfl_xor(v, 8));
            if (lr == 0) {
                const int gi = row0 + wr * 64 + fi * 16 + lg * 4 + jj;
                atomicMin(&minkey[gi], __float_as_uint(fmaxf(sq[gi] + v, 0.f)));
            }
        }

    // fused finalization: last of the 8 blocks for this row panel writes out
    __threadfence();
    __syncthreads();
    if (tid == 0) sflag = atomicAdd(&ctr[bi], 1u);
    __syncthreads();
    if (sflag == 7u && tid < 256) {
        __threadfence();
        const int gi = row0 + tid;
        u32 mk = atomicAdd(&minkey[gi], 0u);   // coherent read
        u32 ab = atomicOr(&ap2[gi], 0u);       // coherent read
        out[gi] = fmaxf(sqrtf(__uint_as_float(ab)) - sqrtf(__uint_as_float(mk)) + 1.f,
                        0.f);
    }
}

extern "C" void kernel_launch(void* const* d_in, const int* in_sizes, int n_in,
                              void* d_out, int out_size, void* d_ws, size_t ws_size,
                              hipStream_t stream) {
    const float* x = (const float*)d_in[0];
    float* out = (float*)d_out;

    char* ws = (char*)d_ws;
    u16* xbf = (u16*)ws;                                // 2 MB bf16 copy
    float* sq = (float*)(ws + 2097152);                 // 32 KB
    u32* minkey = (u32*)(ws + 2097152 + 32768);         // 32 KB
    u32* ap2 = (u32*)(ws + 2097152 + 65536);            // 32 KB
    u32* ctr = (u32*)(ws + 2097152 + 98304);            // 128 B

    k_prep<<<N / 16, 256, 0, stream>>>(x, xbf, sq, minkey, ctr);
    k_neg<<<dim3(32, 8), 512, 0, stream>>>(xbf, sq, minkey, ap2, ctr, out);
}

// Round 8
// 65.240 us; speedup vs baseline: 1.2699x; 1.0163x over previous
//
#include <hip/hip_runtime.h>

#define N 8192
#define D 128

typedef __attribute__((ext_vector_type(8))) short bf16x8;
typedef __attribute__((ext_vector_type(4))) float f32x4;
typedef unsigned int u32;
typedef unsigned short u16;

__device__ __forceinline__ u16 f2bf(float f) {
    u32 u = __float_as_uint(f);
    u += 0x7FFF + ((u >> 16) & 1);   // round-to-nearest-even
    return (u16)(u >> 16);
}

// async global->LDS, 16B/lane; dst base wave-uniform (HW adds lane*16)
__device__ __forceinline__ void gl_lds16(const u16* g, u16* l) {
    __builtin_amdgcn_global_load_lds(
        (const __attribute__((address_space(1))) u32*)g,
        (__attribute__((address_space(3))) u32*)l, 16, 0, 0);
}

// ---- kernel 1: streaming bf16 copy + row sqnorm + init ---------------------
__global__ __launch_bounds__(256) void k_prep(const float* __restrict__ x,
                                              u16* __restrict__ xbf,
                                              float* __restrict__ sq,
                                              u32* __restrict__ minkey,
                                              u32* __restrict__ ctr) {
    const int tid = threadIdx.x;
    const int r = blockIdx.x * 16 + (tid >> 4);
    const int lr = tid & 15;
    const float4* src = (const float4*)(x + (size_t)r * D + lr * 8);
    float4 v0 = src[0], v1 = src[1];
    union { u16 h[8]; uint4 v; } o;
    o.h[0] = f2bf(v0.x); o.h[1] = f2bf(v0.y); o.h[2] = f2bf(v0.z); o.h[3] = f2bf(v0.w);
    o.h[4] = f2bf(v1.x); o.h[5] = f2bf(v1.y); o.h[6] = f2bf(v1.z); o.h[7] = f2bf(v1.w);
    *(uint4*)(xbf + (size_t)r * D + lr * 8) = o.v;
    float s = v0.x * v0.x + v0.y * v0.y + v0.z * v0.z + v0.w * v0.w
            + v1.x * v1.x + v1.y * v1.y + v1.z * v1.z + v1.w * v1.w;
    s += __shfl_xor(s, 1); s += __shfl_xor(s, 2);
    s += __shfl_xor(s, 4); s += __shfl_xor(s, 8);
    if (lr == 0) { sq[r] = s; minkey[r] = 0xFFFFFFFFu; }
    if (blockIdx.x == 0 && tid < 32) ctr[tid] = 0;
}

// ---- kernel 2: gram via MFMA; A pinned in regs, B dbuf LDS -----------------
// grid (32,8): block = rows [bi*256,+256) x cols [cg*1024,+1024), 8 waves.
__global__ __launch_bounds__(512, 1) void k_neg(const u16* __restrict__ xbf,
                                                const float* __restrict__ sq,
                                                u32* __restrict__ minkey,
                                                u32* __restrict__ ap2,
                                                u32* __restrict__ ctr,
                                                float* __restrict__ out) {
    __shared__ __align__(16) u16 Bl[2][128 * 128];   // 2 x 32 KB
    __shared__ u32 sflag;

    const int bi = blockIdx.x;          // row panel (256 rows)
    const int cg = blockIdx.y;          // col group (1024 cols)
    const int row0 = bi * 256, col00 = cg * 1024;
    const int tid = threadIdx.x;
    const int lane = tid & 63, wave = tid >> 6;
    const int lr = lane & 15, lg = lane >> 4;
    const int wr = wave >> 1, wc = wave & 1;
    const float INF = __int_as_float(0x7F800000);

    // this wave's diagonal tile index (cluster-aligned): fj==fi frags are
    // exactly the same-cluster 16-block there.
    const int tdiag = (cg == (bi >> 2) && wc == (wr & 1))
                      ? 2 * (bi & 3) + (wr >> 1) : -1;

    // stage B tile 0 (swizzle via pre-swizzled global chunk)
#pragma unroll
    for (int it = 0; it < 4; ++it) {
        const int rb0 = wave * 16 + it * 4;
        const int r = rb0 + (lane >> 4);
        gl_lds16(xbf + (size_t)(col00 + r) * D + ((lr ^ (r & 7)) * 8),
                 Bl[0] + rb0 * 128);
    }

    // A fragments: 64 rows x 128 K (64 VGPR), loaded ONCE. The asm identity
    // makes each value opaque so the compiler cannot sink/rematerialize the
    // loads into the K-loop (R6/R7: VGPR_Count 112-128 proved it did).
    bf16x8 af[4][4];
#pragma unroll
    for (int f = 0; f < 4; ++f)
#pragma unroll
        for (int kk = 0; kk < 4; ++kk)
            af[f][kk] = *(const bf16x8*)(xbf +
                (size_t)(row0 + wr * 64 + f * 16 + lr) * D + kk * 32 + lg * 8);
#pragma unroll
    for (int f = 0; f < 4; ++f)
#pragma unroll
        for (int kk = 0; kk < 4; ++kk)
            asm volatile("" : "+v"(af[f][kk]));   // pin: value now opaque

    float rmin[4][4] = {{INF, INF, INF, INF}, {INF, INF, INF, INF},
                        {INF, INF, INF, INF}, {INF, INF, INF, INF}};

    __syncthreads();   // B0 resident

#pragma unroll
    for (int t = 0; t < 8; ++t) {
        const int c0 = col00 + t * 128;
        if (t + 1 < 8) {   // prefetch next B tile before compute
            const int c0n = c0 + 128;
#pragma unroll
            for (int it = 0; it < 4; ++it) {
                const int rb0 = wave * 16 + it * 4;
                const int r = rb0 + (lane >> 4);
                gl_lds16(xbf + (size_t)(c0n + r) * D + ((lr ^ (r & 7)) * 8),
                         Bl[(t + 1) & 1] + rb0 * 128);
            }
        }

        // sq for this tile's col fragments (consumed after MFMA)
        float sjv[4];
#pragma unroll
        for (int fj = 0; fj < 4; ++fj)
            sjv[fj] = sq[c0 + wc * 64 + fj * 16 + lr];

        const u16* Bp = Bl[t & 1];     // static buffer per unrolled body
        f32x4 acc[4][4] = {};
#pragma unroll
        for (int kk = 0; kk < 4; ++kk) {
            const int kx = (kk * 64 + lg * 16) ^ ((lr & 7) << 4);
            bf16x8 bq[4];
#pragma unroll
            for (int fj = 0; fj < 4; ++fj)
                bq[fj] = *(const bf16x8*)((const char*)Bp +
                         (wc * 64 + fj * 16 + lr) * 256 + kx);
#pragma unroll
            for (int fi = 0; fi < 4; ++fi)
#pragma unroll
                for (int fj = 0; fj < 4; ++fj)
                    acc[fi][fj] = __builtin_amdgcn_mfma_f32_16x16x32_bf16(
                        af[fi][kk], bq[fj], acc[fi][fj], 0, 0, 0);
        }

        if (t == tdiag) {
#pragma unroll
            for (int fi = 0; fi < 4; ++fi) {
                float rmx[4] = {-INF, -INF, -INF, -INF};
#pragma unroll
                for (int jj = 0; jj < 4; ++jj)
#pragma unroll
                    for (int fj = 0; fj < 4; ++fj) {
                        float v = fmaf(-2.f, acc[fi][fj][jj], sjv[fj]);
                        if (fj == fi) rmx[jj] = fmaxf(rmx[jj], v);
                        else rmin[fi][jj] = fminf(rmin[fi][jj], v);
                    }
#pragma unroll
                for (int jj = 0; jj < 4; ++jj) {
                    float v = rmx[jj];
                    v = fmaxf(v, __shfl_xor(v, 1));
                    v = fmaxf(v, __shfl_xor(v, 2));
                    v = fmaxf(v, __shfl_xor(v, 4));
                    v = fmaxf(v, __shfl_xor(v, 8));
                    if (lr == 0) {
                        const int gi = row0 + wr * 64 + fi * 16 + lg * 4 + jj;
                        ap2[gi] = __float_as_uint(fmaxf(sq[gi] + v, 0.f));
                    }
                }
            }
        } else {
#pragma unroll
            for (int fi = 0; fi < 4; ++fi)
#pragma unroll
                for (int jj = 0; jj < 4; ++jj)
#pragma unroll
                    for (int fj = 0; fj < 4; ++fj)
                        rmin[fi][jj] = fminf(rmin[fi][jj],
                                             fmaf(-2.f, acc[fi][fj][jj], sjv[fj]));
        }

        __syncthreads();   // drains next-tile staging + read fence
    }

    // per-wave reduce + one atomicMin per row
#pragma unroll
    for (int fi = 0; fi < 4; ++fi)
#pragma unroll
        for (int jj = 0; jj < 4; ++jj) {
            float v = rmin[fi][jj];
            v = fminf(v, __shfl_xor(v, 1));
            v = fminf(v, __shfl_xor(v, 2));
            v = fminf(v, __shfl_xor(v, 4));
            v = fminf(v, __shfl_xor(v, 8));
            if (lr == 0) {
                const int gi = row0 + wr * 64 + fi * 16 + lg * 4 + jj;
                atomicMin(&minkey[gi], __float_as_uint(fmaxf(sq[gi] + v, 0.f)));
            }
        }

    // fused finalization: last of the 8 blocks for this row panel writes out
    __threadfence();
    __syncthreads();
    if (tid == 0) sflag = atomicAdd(&ctr[bi], 1u);
    __syncthreads();
    if (sflag == 7u && tid < 256) {
        __threadfence();
        const int gi = row0 + tid;
        u32 mk = atomicAdd(&minkey[gi], 0u);   // coherent read
        u32 ab = atomicOr(&ap2[gi], 0u);       // coherent read
        out[gi] = fmaxf(sqrtf(__uint_as_float(ab)) - sqrtf(__uint_as_float(mk)) + 1.f,
                        0.f);
    }
}

extern "C" void kernel_launch(void* const* d_in, const int* in_sizes, int n_in,
                              void* d_out, int out_size, void* d_ws, size_t ws_size,
                              hipStream_t stream) {
    const float* x = (const float*)d_in[0];
    float* out = (float*)d_out;

    char* ws = (char*)d_ws;
    u16* xbf = (u16*)ws;                                // 2 MB bf16 copy
    float* sq = (float*)(ws + 2097152);                 // 32 KB
    u32* minkey = (u32*)(ws + 2097152 + 32768);         // 32 KB
    u32* ap2 = (u32*)(ws + 2097152 + 65536);            // 32 KB
    u32* ctr = (u32*)(ws + 2097152 + 98304);            // 128 B

    k_prep<<<N / 16, 256, 0, stream>>>(x, xbf, sq, minkey, ctr);
    k_neg<<<dim3(32, 8), 512, 0, stream>>>(xbf, sq, minkey, ap2, ctr, out);
}

// Round 9
// 65.073 us; speedup vs baseline: 1.2731x; 1.0026x over previous
//
#include <hip/hip_runtime.h>

#define N 8192
#define D 128

typedef __attribute__((ext_vector_type(8))) short bf16x8;
typedef __attribute__((ext_vector_type(4))) float f32x4;
typedef unsigned int u32;
typedef unsigned short u16;

__device__ __forceinline__ u16 f2bf(float f) {
    u32 u = __float_as_uint(f);
    u += 0x7FFF + ((u >> 16) & 1);   // round-to-nearest-even
    return (u16)(u >> 16);
}

// async global->LDS, 16B/lane; dst base wave-uniform (HW adds lane*16)
__device__ __forceinline__ void gl_lds16(const u16* g, u16* l) {
    __builtin_amdgcn_global_load_lds(
        (const __attribute__((address_space(1))) u32*)g,
        (__attribute__((address_space(3))) u32*)l, 16, 0, 0);
}

// ---- kernel 1: streaming bf16 copy + row sqnorm + init ---------------------
__global__ __launch_bounds__(256) void k_prep(const float* __restrict__ x,
                                              u16* __restrict__ xbf,
                                              float* __restrict__ sq,
                                              u32* __restrict__ minkey,
                                              u32* __restrict__ ctr) {
    const int tid = threadIdx.x;
    const int r = blockIdx.x * 16 + (tid >> 4);
    const int lr = tid & 15;
    const float4* src = (const float4*)(x + (size_t)r * D + lr * 8);
    float4 v0 = src[0], v1 = src[1];
    union { u16 h[8]; uint4 v; } o;
    o.h[0] = f2bf(v0.x); o.h[1] = f2bf(v0.y); o.h[2] = f2bf(v0.z); o.h[3] = f2bf(v0.w);
    o.h[4] = f2bf(v1.x); o.h[5] = f2bf(v1.y); o.h[6] = f2bf(v1.z); o.h[7] = f2bf(v1.w);
    *(uint4*)(xbf + (size_t)r * D + lr * 8) = o.v;
    float s = v0.x * v0.x + v0.y * v0.y + v0.z * v0.z + v0.w * v0.w
            + v1.x * v1.x + v1.y * v1.y + v1.z * v1.z + v1.w * v1.w;
    s += __shfl_xor(s, 1); s += __shfl_xor(s, 2);
    s += __shfl_xor(s, 4); s += __shfl_xor(s, 8);
    if (lr == 0) { sq[r] = s; minkey[r] = 0xFFFFFFFFu; }
    if (blockIdx.x == 0 && tid < 32) ctr[tid] = 0;
}

// ---- kernel 2: R4 skeleton — A resident in LDS, B dbuf via global_load_lds -
// grid (32,8): block = rows [bi*256,+256) x cols [cg*1024,+1024), 8 waves.
// LDS: A 64KB + B 2x32KB = 128KB -> 1 block/CU.
__global__ __launch_bounds__(512, 2) void k_neg(const u16* __restrict__ xbf,
                                                const float* __restrict__ sq,
                                                u32* __restrict__ minkey,
                                                u32* __restrict__ ap2,
                                                u32* __restrict__ ctr,
                                                float* __restrict__ out) {
    __shared__ __align__(16) u16 Al[256 * 128];       // 64 KB
    __shared__ __align__(16) u16 Bl[2][128 * 128];    // 2 x 32 KB
    __shared__ u32 sflag;

    const int bi = blockIdx.x;          // row panel (256 rows)
    const int cg = blockIdx.y;          // col group (1024 cols)
    const int row0 = bi * 256, col00 = cg * 1024;
    const int tid = threadIdx.x;
    const int lane = tid & 63, wave = tid >> 6;
    const int lr = lane & 15, lg = lane >> 4;
    const int wr = wave >> 1, wc = wave & 1;
    const float INF = __int_as_float(0x7F800000);

    // statically-derived diagonal tile for this wave (64-row block g64):
    // its 64x64 self-block appears in col-group g64>>4, col-half g64&1,
    // tile (g64&15)>>1. There, fragment fi==fj is exactly one 16-cluster.
    const int g64 = bi * 4 + wr;
    const int tdiag = (cg == (g64 >> 4) && wc == (g64 & 1)) ? ((g64 & 15) >> 1) : -1;

    // stage A panel: 256 rows, 8 gl_lds per wave (swizzle via global chunk)
#pragma unroll
    for (int it = 0; it < 8; ++it) {
        const int ra0 = wave * 32 + it * 4;
        const int r = ra0 + (lane >> 4);
        gl_lds16(xbf + (size_t)(row0 + r) * D + ((lr ^ (r & 7)) * 8),
                 Al + ra0 * 128);
    }
    // stage B tile 0
#pragma unroll
    for (int it = 0; it < 4; ++it) {
        const int rb0 = wave * 16 + it * 4;
        const int r = rb0 + (lane >> 4);
        gl_lds16(xbf + (size_t)(col00 + r) * D + ((lr ^ (r & 7)) * 8),
                 Bl[0] + rb0 * 128);
    }
    __syncthreads();   // A + B0 resident

    float rmin[4][4] = {{INF, INF, INF, INF}, {INF, INF, INF, INF},
                        {INF, INF, INF, INF}, {INF, INF, INF, INF}};
    int cur = 0;

    for (int t = 0; t < 8; ++t) {
        const int c0 = col00 + t * 128;
        if (t + 1 < 8) {   // prefetch next B tile before compute
            const int c0n = c0 + 128;
#pragma unroll
            for (int it = 0; it < 4; ++it) {
                const int rb0 = wave * 16 + it * 4;
                const int r = rb0 + (lane >> 4);
                gl_lds16(xbf + (size_t)(c0n + r) * D + ((lr ^ (r & 7)) * 8),
                         Bl[cur ^ 1] + rb0 * 128);
            }
        }

        float sjv[4];
#pragma unroll
        for (int fj = 0; fj < 4; ++fj)
            sjv[fj] = sq[c0 + wc * 64 + fj * 16 + lr];

        const u16* Bp = Bl[cur];
        f32x4 acc[4][4] = {};
#pragma unroll
        for (int kk = 0; kk < 4; ++kk) {
            const int kx = (kk * 64 + lg * 16) ^ ((lr & 7) << 4);
            bf16x8 af[4], bq[4];
#pragma unroll
            for (int f = 0; f < 4; ++f) {
                af[f] = *(const bf16x8*)((const char*)Al +
                        (wr * 64 + f * 16 + lr) * 256 + kx);
                bq[f] = *(const bf16x8*)((const char*)Bp +
                        (wc * 64 + f * 16 + lr) * 256 + kx);
            }
#pragma unroll
            for (int fi = 0; fi < 4; ++fi)
#pragma unroll
                for (int fj = 0; fj < 4; ++fj)
                    acc[fi][fj] = __builtin_amdgcn_mfma_f32_16x16x32_bf16(
                        af[fi], bq[fj], acc[fi][fj], 0, 0, 0);
        }

        if (t == tdiag) {
#pragma unroll
            for (int fi = 0; fi < 4; ++fi) {
                float rmx[4] = {-INF, -INF, -INF, -INF};
#pragma unroll
                for (int jj = 0; jj < 4; ++jj)
#pragma unroll
                    for (int fj = 0; fj < 4; ++fj) {
                        float v = fmaf(-2.f, acc[fi][fj][jj], sjv[fj]);
                        if (fj == fi) rmx[jj] = fmaxf(rmx[jj], v);
                        else rmin[fi][jj] = fminf(rmin[fi][jj], v);
                    }
#pragma unroll
                for (int jj = 0; jj < 4; ++jj) {
                    float v = rmx[jj];
                    v = fmaxf(v, __shfl_xor(v, 1));
                    v = fmaxf(v, __shfl_xor(v, 2));
                    v = fmaxf(v, __shfl_xor(v, 4));
                    v = fmaxf(v, __shfl_xor(v, 8));
                    if (lr == 0) {
                        const int gi = row0 + wr * 64 + fi * 16 + lg * 4 + jj;
                        ap2[gi] = __float_as_uint(fmaxf(sq[gi] + v, 0.f));
                    }
                }
            }
        } else {
#pragma unroll
            for (int fi = 0; fi < 4; ++fi)
#pragma unroll
                for (int jj = 0; jj < 4; ++jj)
#pragma unroll
                    for (int fj = 0; fj < 4; ++fj)
                        rmin[fi][jj] = fminf(rmin[fi][jj],
                                             fmaf(-2.f, acc[fi][fj][jj], sjv[fj]));
        }

        __syncthreads();   // drains next-tile staging + read fence
        cur ^= 1;
    }

    // per-wave reduce + one atomicMin per row
#pragma unroll
    for (int fi = 0; fi < 4; ++fi)
#pragma unroll
        for (int jj = 0; jj < 4; ++jj) {
            float v = rmin[fi][jj];
            v = fminf(v, __shfl_xor(v, 1));
            v = fminf(v, __shfl_xor(v, 2));
            v = fminf(v, __shfl_xor(v, 4));
            v = fminf(v, __shfl_xor(v, 8));
            if (lr == 0) {
                const int gi = row0 + wr * 64 + fi * 16 + lg * 4 + jj;
                atomicMin(&minkey[gi], __float_as_uint(fmaxf(sq[gi] + v, 0.f)));
            }
        }

    // fused finalization: last of the 8 blocks for this row panel writes out
    __threadfence();
    __syncthreads();
    if (tid == 0) sflag = atomicAdd(&ctr[bi], 1u);
    __syncthreads();
    if (sflag == 7u && tid < 256) {
        __threadfence();
        const int gi = row0 + tid;
        u32 mk = atomicAdd(&minkey[gi], 0u);   // coherent read
        u32 ab = atomicOr(&ap2[gi], 0u);       // coherent read
        out[gi] = fmaxf(sqrtf(__uint_as_float(ab)) - sqrtf(__uint_as_float(mk)) + 1.f,
                        0.f);
    }
}

extern "C" void kernel_launch(void* const* d_in, const int* in_sizes, int n_in,
                              void* d_out, int out_size, void* d_ws, size_t ws_size,
                              hipStream_t stream) {
    const float* x = (const float*)d_in[0];
    float* out = (float*)d_out;

    char* ws = (char*)d_ws;
    u16* xbf = (u16*)ws;                                // 2 MB bf16 copy
    float* sq = (float*)(ws + 2097152);                 // 32 KB
    u32* minkey = (u32*)(ws + 2097152 + 32768);         // 32 KB
    u32* ap2 = (u32*)(ws + 2097152 + 65536);            // 32 KB
    u32* ctr = (u32*)(ws + 2097152 + 98304);            // 128 B

    k_prep<<<N / 16, 256, 0, stream>>>(x, xbf, sq, minkey, ctr);
    k_neg<<<dim3(32, 8), 512, 0, stream>>>(xbf, sq, minkey, ap2, ctr, out);
}

// Round 10
// 44.763 us; speedup vs baseline: 1.8508x; 1.4537x over previous
//
#include <hip/hip_runtime.h>

#define N 8192
#define D 128

typedef __attribute__((ext_vector_type(8))) short bf16x8;
typedef __attribute__((ext_vector_type(4))) float f32x4;
typedef unsigned int u32;
typedef unsigned short u16;

__device__ __forceinline__ u16 f2bf(float f) {
    u32 u = __float_as_uint(f);
    u += 0x7FFF + ((u >> 16) & 1);   // round-to-nearest-even
    return (u16)(u >> 16);
}

// async global->LDS, 16B/lane; dst base wave-uniform (HW adds lane*16)
__device__ __forceinline__ void gl_lds16(const u16* g, u16* l) {
    __builtin_amdgcn_global_load_lds(
        (const __attribute__((address_space(1))) u32*)g,
        (__attribute__((address_space(3))) u32*)l, 16, 0, 0);
}

// ---- kernel 1: streaming bf16 copy + row sqnorm + init ---------------------
__global__ __launch_bounds__(256) void k_prep(const float* __restrict__ x,
                                              u16* __restrict__ xbf,
                                              float* __restrict__ sq,
                                              u32* __restrict__ minkey,
                                              u32* __restrict__ ctr) {
    const int tid = threadIdx.x;
    const int r = blockIdx.x * 16 + (tid >> 4);
    const int lr = tid & 15;
    const float4* src = (const float4*)(x + (size_t)r * D + lr * 8);
    float4 v0 = src[0], v1 = src[1];
    union { u16 h[8]; uint4 v; } o;
    o.h[0] = f2bf(v0.x); o.h[1] = f2bf(v0.y); o.h[2] = f2bf(v0.z); o.h[3] = f2bf(v0.w);
    o.h[4] = f2bf(v1.x); o.h[5] = f2bf(v1.y); o.h[6] = f2bf(v1.z); o.h[7] = f2bf(v1.w);
    *(uint4*)(xbf + (size_t)r * D + lr * 8) = o.v;
    float s = v0.x * v0.x + v0.y * v0.y + v0.z * v0.z + v0.w * v0.w
            + v1.x * v1.x + v1.y * v1.y + v1.z * v1.z + v1.w * v1.w;
    s += __shfl_xor(s, 1); s += __shfl_xor(s, 2);
    s += __shfl_xor(s, 4); s += __shfl_xor(s, 8);
    if (lr == 0) { sq[r] = s; minkey[r] = 0xFFFFFFFFu; }
    if (blockIdx.x == 0 && tid < 32) ctr[tid] = 0;
}

// ---- kernel 2: A resident in LDS, B dbuf via global_load_lds ---------------
// grid (32,8): block = rows [bi*256,+256) x cols [cg*1024,+1024), 8 waves.
// NO __threadfence anywhere: agent-scope fence = buffer_wbl2+inv = nukes the
// XCD's L2 (R5-R9 regression, 60-83us). Cross-block visibility is handled by
// device-scope atomics only.
__global__ __launch_bounds__(512, 2) void k_neg(const u16* __restrict__ xbf,
                                                const float* __restrict__ sq,
                                                u32* __restrict__ minkey,
                                                u32* __restrict__ ap2,
                                                u32* __restrict__ ctr,
                                                float* __restrict__ out) {
    __shared__ __align__(16) u16 Al[256 * 128];       // 64 KB
    __shared__ __align__(16) u16 Bl[2][128 * 128];    // 2 x 32 KB
    __shared__ u32 sflag;

    const int bi = blockIdx.x;          // row panel (256 rows)
    const int cg = blockIdx.y;          // col group (1024 cols)
    const int row0 = bi * 256, col00 = cg * 1024;
    const int tid = threadIdx.x;
    const int lane = tid & 63, wave = tid >> 6;
    const int lr = lane & 15, lg = lane >> 4;
    const int wr = wave >> 1, wc = wave & 1;
    const float INF = __int_as_float(0x7F800000);

    // statically-derived diagonal tile for this wave's 64-row block g64
    const int g64 = bi * 4 + wr;
    const int tdiag = (cg == (g64 >> 4) && wc == (g64 & 1)) ? ((g64 & 15) >> 1) : -1;

    // stage A panel (swizzle via pre-swizzled global chunk)
#pragma unroll
    for (int it = 0; it < 8; ++it) {
        const int ra0 = wave * 32 + it * 4;
        const int r = ra0 + (lane >> 4);
        gl_lds16(xbf + (size_t)(row0 + r) * D + ((lr ^ (r & 7)) * 8),
                 Al + ra0 * 128);
    }
    // stage B tile 0
#pragma unroll
    for (int it = 0; it < 4; ++it) {
        const int rb0 = wave * 16 + it * 4;
        const int r = rb0 + (lane >> 4);
        gl_lds16(xbf + (size_t)(col00 + r) * D + ((lr ^ (r & 7)) * 8),
                 Bl[0] + rb0 * 128);
    }
    __syncthreads();   // A + B0 resident

    float rmin[4][4] = {{INF, INF, INF, INF}, {INF, INF, INF, INF},
                        {INF, INF, INF, INF}, {INF, INF, INF, INF}};
    int cur = 0;

    for (int t = 0; t < 8; ++t) {
        const int c0 = col00 + t * 128;
        if (t + 1 < 8) {   // prefetch next B tile before compute
            const int c0n = c0 + 128;
#pragma unroll
            for (int it = 0; it < 4; ++it) {
                const int rb0 = wave * 16 + it * 4;
                const int r = rb0 + (lane >> 4);
                gl_lds16(xbf + (size_t)(c0n + r) * D + ((lr ^ (r & 7)) * 8),
                         Bl[cur ^ 1] + rb0 * 128);
            }
        }

        float sjv[4];
#pragma unroll
        for (int fj = 0; fj < 4; ++fj)
            sjv[fj] = sq[c0 + wc * 64 + fj * 16 + lr];

        const u16* Bp = Bl[cur];
        f32x4 acc[4][4] = {};
#pragma unroll
        for (int kk = 0; kk < 4; ++kk) {
            const int kx = (kk * 64 + lg * 16) ^ ((lr & 7) << 4);
            bf16x8 af[4], bq[4];
#pragma unroll
            for (int f = 0; f < 4; ++f) {
                af[f] = *(const bf16x8*)((const char*)Al +
                        (wr * 64 + f * 16 + lr) * 256 + kx);
                bq[f] = *(const bf16x8*)((const char*)Bp +
                        (wc * 64 + f * 16 + lr) * 256 + kx);
            }
#pragma unroll
            for (int fi = 0; fi < 4; ++fi)
#pragma unroll
                for (int fj = 0; fj < 4; ++fj)
                    acc[fi][fj] = __builtin_amdgcn_mfma_f32_16x16x32_bf16(
                        af[fi], bq[fj], acc[fi][fj], 0, 0, 0);
        }

        if (t == tdiag) {
#pragma unroll
            for (int fi = 0; fi < 4; ++fi) {
                float rmx[4] = {-INF, -INF, -INF, -INF};
#pragma unroll
                for (int jj = 0; jj < 4; ++jj)
#pragma unroll
                    for (int fj = 0; fj < 4; ++fj) {
                        float v = fmaf(-2.f, acc[fi][fj][jj], sjv[fj]);
                        if (fj == fi) rmx[jj] = fmaxf(rmx[jj], v);
                        else rmin[fi][jj] = fminf(rmin[fi][jj], v);
                    }
#pragma unroll
                for (int jj = 0; jj < 4; ++jj) {
                    float v = rmx[jj];
                    v = fmaxf(v, __shfl_xor(v, 1));
                    v = fmaxf(v, __shfl_xor(v, 2));
                    v = fmaxf(v, __shfl_xor(v, 4));
                    v = fmaxf(v, __shfl_xor(v, 8));
                    if (lr == 0) {
                        const int gi = row0 + wr * 64 + fi * 16 + lg * 4 + jj;
                        // device-scope atomic store: cross-XCD visible, no fence
                        atomicExch(&ap2[gi], __float_as_uint(fmaxf(sq[gi] + v, 0.f)));
                    }
                }
            }
        } else {
#pragma unroll
            for (int fi = 0; fi < 4; ++fi)
#pragma unroll
                for (int jj = 0; jj < 4; ++jj)
#pragma unroll
                    for (int fj = 0; fj < 4; ++fj)
                        rmin[fi][jj] = fminf(rmin[fi][jj],
                                             fmaf(-2.f, acc[fi][fj][jj], sjv[fj]));
        }

        __syncthreads();   // drains next-tile staging + read fence
        cur ^= 1;
    }

    // per-wave reduce + one atomicMin per row
#pragma unroll
    for (int fi = 0; fi < 4; ++fi)
#pragma unroll
        for (int jj = 0; jj < 4; ++jj) {
            float v = rmin[fi][jj];
            v = fminf(v, __shfl_xor(v, 1));
            v = fminf(v, __shfl_xor(v, 2));
            v = fminf(v, __shfl_xor(v, 4));
            v = fminf(v, __shfl_xor(v, 8));
            if (lr == 0) {
                const int gi = row0 + wr * 64 + fi * 16 + lg * 4 + jj;
                atomicMin(&minkey[gi], __float_as_uint(fmaxf(sq[gi] + v, 0.f)));
            }
        }

    // fused finalization: last of the 8 blocks for this row panel writes out.
    // __syncthreads drains all waves' atomics (vmcnt 0) before ctr bump.
    __syncthreads();
    if (tid == 0) sflag = atomicAdd(&ctr[bi], 1u);
    __syncthreads();
    if (sflag == 7u && tid < 256) {
        const int gi = row0 + tid;
        u32 mk = atomicAdd(&minkey[gi], 0u);   // device-scope atomic read
        u32 ab = atomicOr(&ap2[gi], 0u);       // device-scope atomic read
        out[gi] = fmaxf(sqrtf(__uint_as_float(ab)) - sqrtf(__uint_as_float(mk)) + 1.f,
                        0.f);
    }
}

extern "C" void kernel_launch(void* const* d_in, const int* in_sizes, int n_in,
                              void* d_out, int out_size, void* d_ws, size_t ws_size,
                              hipStream_t stream) {
    const float* x = (const float*)d_in[0];
    float* out = (float*)d_out;

    char* ws = (char*)d_ws;
    u16* xbf = (u16*)ws;                                // 2 MB bf16 copy
    float* sq = (float*)(ws + 2097152);                 // 32 KB
    u32* minkey = (u32*)(ws + 2097152 + 32768);         // 32 KB
    u32* ap2 = (u32*)(ws + 2097152 + 65536);            // 32 KB
    u32* ctr = (u32*)(ws + 2097152 + 98304);            // 128 B

    k_prep<<<N / 16, 256, 0, stream>>>(x, xbf, sq, minkey, ctr);
    k_neg<<<dim3(32, 8), 512, 0, stream>>>(xbf, sq, minkey, ap2, ctr, out);
}